// Round 14
// baseline (110.924 us; speedup 1.0000x reference)
//
#include <hip/hip_runtime.h>
#include <math.h>

#define D 128
#define B 8
#define T_SAMP 32768
#define K 512
#define NT 8
#define NFRM 128

// ws float-region layout
#define WS_C1   0
#define WS_ENV8 1024
#define WS_SEL  2048
#define WS_VAL  6144
#define WS_B3P  6160
// bf16 fragment-interleaved weight region. Frag (nt,kt) = 512 contiguous elements;
// element (lane,e) holds W[k=32kt+8*(lane>>4)+e][n=16nt+(lane&15)].
#define WSBF_BYTE 32768
#define FP1 0        // pw1 : 8nt x 2kt x 512  (k>=33 zero-padded)
#define FP2 8192     // pw2 : 8nt x 4kt x 512
#define FP3 24576    // pw3
#define FS1 40960    // skw1
#define FS2 57344    // skw2
#define FS3 73728    // skw3: 32nt x 4kt x 512
#define WTOT 139264
#define WS_NEED (WSBF_BYTE + WTOT*2)

typedef __attribute__((ext_vector_type(8))) short short8;
typedef __attribute__((ext_vector_type(4))) float f32x4;

#define LOG2E 1.4426950408889634f

__device__ __forceinline__ float lrelu(float v){ return fmaxf(v, 0.2f*v); }

__device__ __forceinline__ unsigned cvtpk(float lo, float hi){
    unsigned r;
    asm("v_cvt_pk_bf16_f32 %0, %1, %2" : "=v"(r) : "v"(lo), "v"(hi));
    return r;
}
__device__ __forceinline__ unsigned short bfr(float f){
    unsigned u = __builtin_bit_cast(unsigned, f); u += 0x7fffu + ((u>>16)&1u);
    return (unsigned short)(u>>16);
}
__device__ __forceinline__ float bf2f(short s){
    unsigned u = ((unsigned)(unsigned short)s) << 16;
    return __builtin_bit_cast(float, u);
}
__device__ __forceinline__ float exp2fast(float x){
#if __has_builtin(__builtin_amdgcn_exp2f)
    return __builtin_amdgcn_exp2f(x);
#else
    return __expf(x*0.6931471805599453f);
#endif
}
__device__ __forceinline__ float sin_rev(float fr){
#if __has_builtin(__builtin_amdgcn_sinf)
    return __builtin_amdgcn_sinf(fr);
#else
    return __sinf(fr*6.283185307179586f);
#endif
}
__device__ __forceinline__ float cos_rev(float fr){
#if __has_builtin(__builtin_amdgcn_cosf)
    return __builtin_amdgcn_cosf(fr);
#else
    return __cosf(fr*6.283185307179586f);
#endif
}
__device__ __forceinline__ float pe_val(float pf, int j){
    if (j == 0) return pf;
    if (j > 32) return 0.f;
    const bool is_sin = (j <= 16);
    int e = is_sin ? (j + 125) : (j + 109);
    float sc = __builtin_bit_cast(float, ((unsigned)e) << 23);
    float u = pf * sc;
    float fr = u - floorf(u);
    return is_sin ? sin_rev(fr) : cos_rev(fr);
}

// ---------------- prep helper (fp32, tiny) ----------------
__device__ void layer128(const float* __restrict__ in, const float* __restrict__ w,
                         const float* __restrict__ bias, float* __restrict__ outp,
                         int tid, int mode)
{
    int n = tid & 127, bg = tid >> 7;
    const float* i0 = in + (bg*4+0)*D;
    const float* i1 = in + (bg*4+1)*D;
    const float* i2 = in + (bg*4+2)*D;
    const float* i3 = in + (bg*4+3)*D;
    float bb = bias[n];
    float a0=bb,a1=bb,a2=bb,a3=bb;
    #pragma unroll 4
    for (int j=0;j<D;j++){
        float wv = w[j*D+n];
        a0 = fmaf(i0[j], wv, a0);
        a1 = fmaf(i1[j], wv, a1);
        a2 = fmaf(i2[j], wv, a2);
        a3 = fmaf(i3[j], wv, a3);
    }
    if (mode==0){ a0=lrelu(a0);a1=lrelu(a1);a2=lrelu(a2);a3=lrelu(a3); }
    else if (mode==1){ a0=fabsf(a0);a1=fabsf(a1);a2=fabsf(a2);a3=fabsf(a3); }
    outp[(bg*4+0)*D+n]=a0;
    outp[(bg*4+1)*D+n]=a1;
    outp[(bg*4+2)*D+n]=a2;
    outp[(bg*4+3)*D+n]=a3;
}

// block 0: tc chain + values + sel. block 1: env chain + c1 + b3p.
// blocks 2..: fragment-interleaved bf16 weight transpose.
__global__ __launch_bounds__(256) void setup_kernel(
    const float* __restrict__ x, const float* __restrict__ wt,
    const float* __restrict__ tc_w1, const float* __restrict__ tc_b1,
    const float* __restrict__ tc_w2, const float* __restrict__ tc_b2,
    const float* __restrict__ tc_w3, const float* __restrict__ tc_b3,
    const float* __restrict__ env_w1, const float* __restrict__ env_b1,
    const float* __restrict__ env_w2, const float* __restrict__ env_b2,
    const float* __restrict__ env_w3, const float* __restrict__ env_b3,
    const float* __restrict__ sk_w1, const float* __restrict__ sk_b1,
    const float* __restrict__ pos_w1, const float* __restrict__ pos_w2,
    const float* __restrict__ pos_w3, const float* __restrict__ sk_w2,
    const float* __restrict__ sk_w3, const float* __restrict__ sk_b3,
    float* __restrict__ ws)
{
    __shared__ float xl[B*D], buf1[B*D], buf2[B*D];
    __shared__ float lgts[B*NT], pmax[NT*8], mxr[NT];
    __shared__ int idxl[B];
    int tid = threadIdx.x;

    if (blockIdx.x >= 2){
        int idx = (blockIdx.x - 2)*256 + tid;
        if (idx >= WTOT) return;
        unsigned short* wb = (unsigned short*)((char*)ws + WSBF_BYTE);
        int r; const float* Wp; int ncols = D; int nkt = 4; bool p1 = false;
        if (idx < FP2){ r = idx - FP1; Wp = pos_w1; nkt = 2; p1 = true; }
        else if (idx < FP3){ r = idx - FP2; Wp = pos_w2; }
        else if (idx < FS1){ r = idx - FP3; Wp = pos_w3; }
        else if (idx < FS2){ r = idx - FS1; Wp = sk_w1; }
        else if (idx < FS3){ r = idx - FS2; Wp = sk_w2; }
        else { r = idx - FS3; Wp = sk_w3; ncols = K; }
        int frag = r >> 9, lane = (r >> 3) & 63, e = r & 7;
        int nt2 = frag / nkt, kt = frag - nt2*nkt;
        int k = 32*kt + 8*(lane>>4) + e;
        int n = 16*nt2 + (lane&15);
        float v = (p1 && k >= 33) ? 0.f : Wp[k*ncols + n];
        wb[idx] = bfr(v);
        return;
    }

    for (int i=tid;i<B*D;i+=256) xl[i]=x[i];
    __syncthreads();

    if (blockIdx.x == 1){
        for (int i=tid;i<K;i+=256) ws[WS_B3P+i] = sk_b3[i]*LOG2E;
        layer128(xl, env_w1, env_b1, buf1, tid, 0);
        __syncthreads();
        layer128(buf1, env_w2, env_b2, buf2, tid, 0);
        __syncthreads();
        layer128(buf2, env_w3, env_b3, ws+WS_ENV8, tid, 1);
        layer128(xl, sk_w1, sk_b1, ws+WS_C1, tid, 2);
        return;
    }

    // block 0: tc chain + wavetable prep
    layer128(xl, tc_w1, tc_b1, buf1, tid, 0);
    __syncthreads();
    layer128(buf1, tc_w2, tc_b2, buf2, tid, 0);
    __syncthreads();
    if (tid < 64){
        int b = tid>>3, n = tid&7;
        float a = tc_b3[n];
        #pragma unroll 4
        for (int j=0;j<D;j++) a = fmaf(buf2[b*D+j], tc_w3[j*NT+n], a);
        lgts[b*NT+n] = a;
    } else if (tid < 128){
        int r = (tid-64)>>3, p = tid&7;
        float m = -1e30f;
        for (int k=p*64;k<p*64+64;k++) m = fmaxf(m, wt[r*K+k]);
        pmax[r*8+p] = m;
    }
    __syncthreads();
    if (tid < 8){
        int b = tid; float m = -1e30f; int idx = 0;
        for (int n=0;n<NT;n++){ float v = lgts[b*NT+n]; if (v > m){ m=v; idx=n; } }
        float S = 0.f;
        for (int n=0;n<NT;n++) S += expf(lgts[b*NT+n]-m);
        ws[WS_VAL+b] = 1.0f/S;
        idxl[b] = idx;
    } else if (tid < 16){
        int r = tid-8; float m = -1e30f;
        for (int p=0;p<8;p++) m = fmaxf(m, pmax[r*8+p]);
        mxr[r] = m;
    }
    __syncthreads();
    for (int o=tid;o<B*K;o+=256){
        int b = o>>9, k = o&(K-1);
        int id = idxl[b];
        ws[WS_SEL+o] = wt[id*K+k] / (mxr[id] + 1e-8f);
    }
}

// swapped small layer: A-frags preloaded from GLOBAL (frag-interleaved, coalesced);
// B-frags linear from LDS; output written in next layer's B-frag layout.
template<int NKT_IN, bool ACT>
__device__ __forceinline__ void layerF(const short8* aw,
                                       const unsigned char* inb, unsigned char* outb,
                                       const float* biasp, int wv, int lg, int lc)
{
    const f32x4 z = {0.f,0.f,0.f,0.f};
    const int lane16 = (lg*16 + lc)*16;
    const int obase = ((wv>>1)<<10) + (((2*(wv&1) + (lg>>1))*16 + lc)<<4) + ((lg&1)<<3);
    f32x4 bb = z;
    if (biasp) bb = *(const f32x4*)(biasp + 16*wv + 4*lg);
    #pragma unroll
    for (int rt=0;rt<2;rt++){
        f32x4 d = z;
        #pragma unroll
        for (int kt=0;kt<NKT_IN;kt++){
            short8 bf = *(const short8*)(inb + ((rt*NKT_IN+kt)<<10) + lane16);
            d = __builtin_amdgcn_mfma_f32_16x16x32_bf16(aw[kt], bf, d, 0,0,0);
        }
        float o0 = d[0]+bb[0], o1 = d[1]+bb[1], o2 = d[2]+bb[2], o3 = d[3]+bb[3];
        if (ACT){ o0=lrelu(o0); o1=lrelu(o1); o2=lrelu(o2); o3=lrelu(o3); }
        uint2 u; u.x = cvtpk(o0,o1); u.y = cvtpk(o2,o3);
        *(uint2*)(outb + (rt<<12) + obase) = u;
    }
}

// ---------------- synth11: NO w2/w3 LDS staging — operands streamed from L1/L2 ----------------
// All w2/w3 fragment reads are coalesced 1KB global loads (frag-interleaved layout).
// LDS holds only phase-A activations (16KB). Layer2+layer3 are barrier-free per-wave streams.
__global__ __launch_bounds__(512, 2) void synth11(
    const float* __restrict__ pos_b1, const float* __restrict__ pos_b2,
    const float* __restrict__ pos_b3, const float* __restrict__ sk_b2,
    const float* __restrict__ ws, float* __restrict__ out)
{
    __shared__ __align__(16) unsigned char lds[16384];
    unsigned char* abA = lds;
    unsigned char* abB = lds + 8192;
    unsigned char* PEb = abB;

    const int tid = threadIdx.x;
    const int wv = tid >> 6, lane = tid & 63, lg = lane >> 4, lc = lane & 15;
    const int t0 = blockIdx.x * 32;
    const unsigned short* wg16 = (const unsigned short*)((const char*)ws + WSBF_BYTE);
    const f32x4 z = {0.f,0.f,0.f,0.f};

    // ---- prefetch g1 A-frags (coalesced) + build pe (frag-interleaved) ----
    short8 aw1[2];
    #pragma unroll
    for (int kt=0;kt<2;kt++)
        aw1[kt] = *(const short8*)(wg16 + FP1 + ((wv*2+kt)<<9) + lane*8);
    for (int i = tid; i < 1024; i += 512){
        int r = i >> 5, p = i & 31;
        int j0 = 2*p;
        float pf = (float)(-1.0 + 2.0*(double)(t0+r)/32767.0);
        float v0 = pe_val(pf, j0);
        float v1 = pe_val(pf, j0+1);
        int kt = j0 >> 5, rem = j0 & 31;
        int by = (((r>>4)*2 + kt)<<10) + (((rem>>3)*16 + (r&15))<<4) + (rem&7)*2;
        *(unsigned*)(PEb + by) = cvtpk(v0, v1);
    }
    __syncthreads();

    // ---- phase A: issue next layer's frags before current MFMAs ----
    short8 awn[4];
    #pragma unroll
    for (int kt=0;kt<4;kt++)
        awn[kt] = *(const short8*)(wg16 + FP2 + ((wv*4+kt)<<9) + lane*8);
    layerF<2,true>(aw1, PEb, abA, pos_b1, wv, lg, lc);          // g1: pe -> abA
    __syncthreads();
    {
        short8 awp[4];
        #pragma unroll
        for (int kt=0;kt<4;kt++)
            awp[kt] = *(const short8*)(wg16 + FP3 + ((wv*4+kt)<<9) + lane*8);
        layerF<4,true>(awn, abA, abB, pos_b2, wv, lg, lc);      // g2: abA -> abB
        #pragma unroll
        for (int kt=0;kt<4;kt++) awn[kt] = awp[kt];
    }
    __syncthreads();
    {
        short8 awp[4];
        #pragma unroll
        for (int kt=0;kt<4;kt++)
            awp[kt] = *(const short8*)(wg16 + FS1 + ((wv*4+kt)<<9) + lane*8);
        layerF<4,false>(awn, abB, abA, pos_b3, wv, lg, lc);     // P: abB -> abA
        #pragma unroll
        for (int kt=0;kt<4;kt++) awn[kt] = awp[kt];
    }
    __syncthreads();
    layerF<4,false>(awn, abA, abB, nullptr, wv, lg, lc);        // A1: abA -> abB
    __syncthreads();

    // ---- h1 frags from abB + c1 (last LDS use; no barriers after this) ----
    short8 hf[2][4];
    {
        const int b = lc & 7;
        const float* c1g = ws + WS_C1 + b*128;
        #pragma unroll
        for (int rtl=0;rtl<2;rtl++){
            int tl = 4*wv + 2*rtl + (lc>>3);
            int fr = tl >> 4, lrow = tl & 15;
            #pragma unroll
            for (int kt=0;kt<4;kt++){
                short8 a1v = *(const short8*)(abB + ((fr*4+kt)<<10) + ((lg*16+lrow)<<4));
                const float* cp = c1g + 32*kt + 8*lg;
                f32x4 c0 = *(const f32x4*)cp;
                f32x4 c1v = *(const f32x4*)(cp+4);
                float h[8];
                #pragma unroll
                for (int e=0;e<4;e++){
                    h[e]   = lrelu(bf2f(a1v[e])   + c0[e]);
                    h[4+e] = lrelu(bf2f(a1v[4+e]) + c1v[e]);
                }
                uint4 t4; t4.x=cvtpk(h[0],h[1]); t4.y=cvtpk(h[2],h[3]);
                t4.z=cvtpk(h[4],h[5]); t4.w=cvtpk(h[6],h[7]);
                hf[rtl][kt] = __builtin_bit_cast(short8, t4);
            }
        }
    }

    // ---- layer2 (swapped, w2 frags streamed from global) + in-register transpose ----
    short8 h2B[2][4];
    {
        const int sA = (2*(lg&1))*16 + lc;
        const int sB = sA + 16;
        const bool hi = (lg>>1) != 0;
        #pragma unroll
        for (int kt2=0; kt2<4; kt2++){
            unsigned dpk[2][2][2];
            #pragma unroll
            for (int p=0;p<2;p++){
                int n2t = 2*kt2+p;
                short8 aw[4];
                #pragma unroll
                for (int kt=0;kt<4;kt++)
                    aw[kt] = *(const short8*)(wg16 + FS2 + ((n2t*4+kt)<<9) + lane*8);
                f32x4 b2 = *(const f32x4*)(sk_b2 + 16*n2t + 4*lg);
                __builtin_amdgcn_s_setprio(1);
                #pragma unroll
                for (int rtl=0;rtl<2;rtl++){
                    f32x4 d = z;
                    #pragma unroll
                    for (int kt=0;kt<4;kt++)
                        d = __builtin_amdgcn_mfma_f32_16x16x32_bf16(aw[kt], hf[rtl][kt], d, 0,0,0);
                    float o0=lrelu(d[0]+b2[0]), o1=lrelu(d[1]+b2[1]);
                    float o2=lrelu(d[2]+b2[2]), o3=lrelu(d[3]+b2[3]);
                    dpk[p][rtl][0] = cvtpk(o0,o1);
                    dpk[p][rtl][1] = cvtpk(o2,o3);
                }
                __builtin_amdgcn_s_setprio(0);
            }
            #pragma unroll
            for (int rtl=0;rtl<2;rtl++){
                unsigned a0 = (unsigned)__shfl((int)dpk[0][rtl][0], sA, 64);
                unsigned b0 = (unsigned)__shfl((int)dpk[1][rtl][0], sA, 64);
                unsigned a1 = (unsigned)__shfl((int)dpk[0][rtl][1], sA, 64);
                unsigned b1 = (unsigned)__shfl((int)dpk[1][rtl][1], sA, 64);
                unsigned a2 = (unsigned)__shfl((int)dpk[0][rtl][0], sB, 64);
                unsigned b2u= (unsigned)__shfl((int)dpk[1][rtl][0], sB, 64);
                unsigned a3 = (unsigned)__shfl((int)dpk[0][rtl][1], sB, 64);
                unsigned b3u= (unsigned)__shfl((int)dpk[1][rtl][1], sB, 64);
                uint4 uu;
                uu.x = hi ? b0 : a0;  uu.y = hi ? b1 : a1;
                uu.z = hi ? b2u : a2; uu.w = hi ? b3u : a3;
                h2B[rtl][kt2] = __builtin_bit_cast(short8, uu);
            }
        }
    }

    // ---- layer3 (swapped): w3 frags streamed from global, barrier-free, fused exp/sel ----
    float SSa[2], WWa[2];
    SSa[0]=0.f; SSa[1]=0.f; WWa[0]=0.f; WWa[1]=0.f;

    const int crot = blockIdx.x & 7;
    const float* selg = ws + WS_SEL + (lc & 7)*512;
    const float* b3g  = ws + WS_B3P;
    #pragma unroll 1
    for (int it=0; it<8; ++it){
        const int c = (crot + it) & 7;
        #pragma unroll
        for (int nl=0;nl<4;nl++){
            int n3t = 4*c + nl;
            short8 bw[4];
            #pragma unroll
            for (int kt=0;kt<4;kt++)
                bw[kt] = *(const short8*)(wg16 + FS3 + ((n3t*4+kt)<<9) + lane*8);
            f32x4 d3[2]; d3[0]=z; d3[1]=z;
            __builtin_amdgcn_s_setprio(1);
            #pragma unroll
            for (int rtl=0;rtl<2;rtl++){
                #pragma unroll
                for (int kt=0;kt<4;kt++)
                    d3[rtl] = __builtin_amdgcn_mfma_f32_16x16x32_bf16(bw[kt], h2B[rtl][kt], d3[rtl], 0,0,0);
            }
            __builtin_amdgcn_s_setprio(0);
            f32x4 b3 = *(const f32x4*)(b3g + 16*n3t + 4*lg);
            f32x4 sv = *(const f32x4*)(selg + 16*n3t + 4*lg);
            #pragma unroll
            for (int rtl=0;rtl<2;rtl++){
                float e0 = exp2fast(fmaf(d3[rtl][0], LOG2E, b3[0]));
                float e1 = exp2fast(fmaf(d3[rtl][1], LOG2E, b3[1]));
                float e2 = exp2fast(fmaf(d3[rtl][2], LOG2E, b3[2]));
                float e3 = exp2fast(fmaf(d3[rtl][3], LOG2E, b3[3]));
                SSa[rtl] += (e0+e1) + (e2+e3);
                float w = fmaf(e0, sv[0], fmaf(e1, sv[1], fmaf(e2, sv[2], e3*sv[3])));
                WWa[rtl] += w;
            }
        }
    }

    // ---- epilogue: reduce over lg, env interp, write ----
    #pragma unroll
    for (int rtl=0;rtl<2;rtl++){
        float s = SSa[rtl];
        float w = WWa[rtl];
        s += __shfl_xor(s, 16, 64); s += __shfl_xor(s, 32, 64);
        w += __shfl_xor(w, 16, 64); w += __shfl_xor(w, 32, 64);
        if (lg == 0){
            int tl = 4*wv + 2*rtl + (lc>>3);
            int b  = lc & 7;
            int t  = t0 + tl;
            float coord = (t + 0.5f)*(1.0f/256.0f) - 0.5f;
            float fi = floorf(coord); float frac = coord - fi;
            int i0 = (int)fi; int i1 = i0 + 1;
            i0 = min(max(i0,0),NFRM-1); i1 = min(max(i1,0),NFRM-1);
            float e0 = ws[WS_ENV8 + b*NFRM + i0], e1 = ws[WS_ENV8 + b*NFRM + i1];
            float envv = e0*(1.0f-frac) + e1*frac;
            out[b*T_SAMP + t] = (w/s) * envv * ws[WS_VAL+b];
        }
    }
}

extern "C" void kernel_launch(void* const* d_in, const int* in_sizes, int n_in,
                              void* d_out, int out_size, void* d_ws, size_t ws_size,
                              hipStream_t stream)
{
    (void)in_sizes; (void)n_in; (void)out_size;
    const float* x       = (const float*)d_in[0];
    const float* wt      = (const float*)d_in[1];
    const float* tc_w1   = (const float*)d_in[2];
    const float* tc_b1   = (const float*)d_in[3];
    const float* tc_w2   = (const float*)d_in[4];
    const float* tc_b2   = (const float*)d_in[5];
    const float* tc_w3   = (const float*)d_in[6];
    const float* tc_b3   = (const float*)d_in[7];
    const float* env_w1  = (const float*)d_in[8];
    const float* env_b1  = (const float*)d_in[9];
    const float* env_w2  = (const float*)d_in[10];
    const float* env_b2  = (const float*)d_in[11];
    const float* env_w3  = (const float*)d_in[12];
    const float* env_b3  = (const float*)d_in[13];
    const float* pos_w1  = (const float*)d_in[14];
    const float* pos_b1  = (const float*)d_in[15];
    const float* pos_w2  = (const float*)d_in[16];
    const float* pos_b2  = (const float*)d_in[17];
    const float* pos_w3  = (const float*)d_in[18];
    const float* pos_b3  = (const float*)d_in[19];
    const float* sk_w1   = (const float*)d_in[20];
    const float* sk_b1   = (const float*)d_in[21];
    const float* sk_w2   = (const float*)d_in[22];
    const float* sk_b2   = (const float*)d_in[23];
    const float* sk_w3   = (const float*)d_in[24];
    const float* sk_b3   = (const float*)d_in[25];
    float* ws  = (float*)d_ws;
    float* out = (float*)d_out;

    if (ws_size < (size_t)WS_NEED) return;  // ws proven >= WS_NEED on this harness

    hipLaunchKernelGGL(setup_kernel, dim3(2 + (WTOT+255)/256), dim3(256), 0, stream,
        x, wt, tc_w1, tc_b1, tc_w2, tc_b2, tc_w3, tc_b3,
        env_w1, env_b1, env_w2, env_b2, env_w3, env_b3,
        sk_w1, sk_b1, pos_w1, pos_w2, pos_w3, sk_w2, sk_w3, sk_b3, ws);

    hipLaunchKernelGGL(synth11, dim3(T_SAMP/32), dim3(512), 0, stream,
        pos_b1, pos_b2, pos_b3, sk_b2, ws, out);
}

// Round 15
// 86.674 us; speedup vs baseline: 1.2798x; 1.2798x over previous
//
#include <hip/hip_runtime.h>
#include <math.h>

#define D 128
#define B 8
#define T_SAMP 32768
#define K 512
#define NT 8
#define NFRM 128

// ws float-region layout
#define WS_C1   0
#define WS_ENV8 1024
#define WS_SEL  2048
#define WS_VAL  6144
#define WS_B3P  6160
// bf16 fragment-interleaved weight region. Frag (nt,kt) = 512 contiguous elements;
// element (lane,e) holds W[k=32kt+8*(lane>>4)+e][n=16nt+(lane&15)].
#define WSBF_BYTE 32768
#define FP1 0        // pw1 : 8nt x 2kt x 512  (k>=33 zero-padded)
#define FP2 8192     // pw2 : 8nt x 4kt x 512
#define FP3 24576    // pw3
#define FS1 40960    // skw1
#define FS2 57344    // skw2
#define FS3 73728    // skw3: 32nt x 4kt x 512
#define WTOT 139264
#define WS_NEED (WSBF_BYTE + WTOT*2)

typedef __attribute__((ext_vector_type(8))) short short8;
typedef __attribute__((ext_vector_type(4))) float f32x4;

#define LOG2E 1.4426950408889634f

__device__ __forceinline__ float lrelu(float v){ return fmaxf(v, 0.2f*v); }

__device__ __forceinline__ unsigned cvtpk(float lo, float hi){
    unsigned r;
    asm("v_cvt_pk_bf16_f32 %0, %1, %2" : "=v"(r) : "v"(lo), "v"(hi));
    return r;
}
__device__ __forceinline__ unsigned short bfr(float f){
    unsigned u = __builtin_bit_cast(unsigned, f); u += 0x7fffu + ((u>>16)&1u);
    return (unsigned short)(u>>16);
}
__device__ __forceinline__ float bf2f(short s){
    unsigned u = ((unsigned)(unsigned short)s) << 16;
    return __builtin_bit_cast(float, u);
}
__device__ __forceinline__ float exp2fast(float x){
#if __has_builtin(__builtin_amdgcn_exp2f)
    return __builtin_amdgcn_exp2f(x);
#else
    return __expf(x*0.6931471805599453f);
#endif
}
__device__ __forceinline__ float sin_rev(float fr){
#if __has_builtin(__builtin_amdgcn_sinf)
    return __builtin_amdgcn_sinf(fr);
#else
    return __sinf(fr*6.283185307179586f);
#endif
}
__device__ __forceinline__ float cos_rev(float fr){
#if __has_builtin(__builtin_amdgcn_cosf)
    return __builtin_amdgcn_cosf(fr);
#else
    return __cosf(fr*6.283185307179586f);
#endif
}
__device__ __forceinline__ float pe_val(float pf, int j){
    if (j == 0) return pf;
    if (j > 32) return 0.f;
    const bool is_sin = (j <= 16);
    int e = is_sin ? (j + 125) : (j + 109);
    float sc = __builtin_bit_cast(float, ((unsigned)e) << 23);
    float u = pf * sc;
    float fr = u - floorf(u);
    return is_sin ? sin_rev(fr) : cos_rev(fr);
}

#define VMCNT0 asm volatile("s_waitcnt vmcnt(0)" ::: "memory")

// ---------------- prep helper: K-split x4 layer (512 threads, latency-shortened) ----------------
// thread (n = tid&127, half = tid>>7): partial over j in [half*32, half*32+32) for ALL 8 batches.
// in[] reads are lane-uniform (broadcast, conflict-free); w reads coalesced.
__device__ void layer128s(const float* __restrict__ in, const float* __restrict__ w,
                          const float* __restrict__ bias, float* __restrict__ outp,
                          float* __restrict__ scratch, int tid, int mode)
{
    int n = tid & 127, half = tid >> 7;       // half 0..3
    float acc[8];
    #pragma unroll
    for (int b=0;b<8;b++) acc[b] = 0.f;
    int j0 = half*32;
    #pragma unroll 4
    for (int j=j0;j<j0+32;j++){
        float wv = w[j*D+n];
        #pragma unroll
        for (int b=0;b<8;b++) acc[b] = fmaf(in[b*D+j], wv, acc[b]);
    }
    if (half){
        #pragma unroll
        for (int b=0;b<8;b++) scratch[((half-1)*8+b)*128+n] = acc[b];
    }
    __syncthreads();
    if (half == 0){
        float bb = bias[n];
        #pragma unroll
        for (int b=0;b<8;b++){
            float a = acc[b] + scratch[(0*8+b)*128+n]
                    + scratch[(1*8+b)*128+n] + scratch[(2*8+b)*128+n] + bb;
            if (mode==0) a = lrelu(a);
            else if (mode==1) a = fabsf(a);
            outp[b*D+n] = a;
        }
    }
    __syncthreads();
}

// block 0: tc chain + values + sel. block 1: env chain + c1 + b3p.
// blocks 2..: fragment-interleaved bf16 weight transpose (512 idx/block).
__global__ __launch_bounds__(512) void setup_kernel(
    const float* __restrict__ x, const float* __restrict__ wt,
    const float* __restrict__ tc_w1, const float* __restrict__ tc_b1,
    const float* __restrict__ tc_w2, const float* __restrict__ tc_b2,
    const float* __restrict__ tc_w3, const float* __restrict__ tc_b3,
    const float* __restrict__ env_w1, const float* __restrict__ env_b1,
    const float* __restrict__ env_w2, const float* __restrict__ env_b2,
    const float* __restrict__ env_w3, const float* __restrict__ env_b3,
    const float* __restrict__ sk_w1, const float* __restrict__ sk_b1,
    const float* __restrict__ pos_w1, const float* __restrict__ pos_w2,
    const float* __restrict__ pos_w3, const float* __restrict__ sk_w2,
    const float* __restrict__ sk_w3, const float* __restrict__ sk_b3,
    float* __restrict__ ws)
{
    __shared__ float xl[B*D], buf1[B*D], buf2[B*D];
    __shared__ float scratch[3*B*128];
    __shared__ float lgts[B*NT], pmax[NT*8], mxr[NT];
    __shared__ int idxl[B];
    int tid = threadIdx.x;

    if (blockIdx.x >= 2){
        int idx = (blockIdx.x - 2)*512 + tid;
        if (idx >= WTOT) return;
        unsigned short* wb = (unsigned short*)((char*)ws + WSBF_BYTE);
        int r; const float* Wp; int ncols = D; int nkt = 4; bool p1 = false;
        if (idx < FP2){ r = idx - FP1; Wp = pos_w1; nkt = 2; p1 = true; }
        else if (idx < FP3){ r = idx - FP2; Wp = pos_w2; }
        else if (idx < FS1){ r = idx - FP3; Wp = pos_w3; }
        else if (idx < FS2){ r = idx - FS1; Wp = sk_w1; }
        else if (idx < FS3){ r = idx - FS2; Wp = sk_w2; }
        else { r = idx - FS3; Wp = sk_w3; ncols = K; }
        int frag = r >> 9, lane = (r >> 3) & 63, e = r & 7;
        int nt2 = frag / nkt, kt = frag - nt2*nkt;
        int k = 32*kt + 8*(lane>>4) + e;
        int n = 16*nt2 + (lane&15);
        float v = (p1 && k >= 33) ? 0.f : Wp[k*ncols + n];
        wb[idx] = bfr(v);
        return;
    }

    for (int i=tid;i<B*D;i+=512) xl[i]=x[i];
    __syncthreads();

    if (blockIdx.x == 1){
        for (int i=tid;i<K;i+=512) ws[WS_B3P+i] = sk_b3[i]*LOG2E;
        layer128s(xl, env_w1, env_b1, buf1, scratch, tid, 0);
        layer128s(buf1, env_w2, env_b2, buf2, scratch, tid, 0);
        layer128s(buf2, env_w3, env_b3, ws+WS_ENV8, scratch, tid, 1);
        layer128s(xl, sk_w1, sk_b1, ws+WS_C1, scratch, tid, 2);
        return;
    }

    // block 0: tc chain + wavetable prep
    layer128s(xl, tc_w1, tc_b1, buf1, scratch, tid, 0);
    layer128s(buf1, tc_w2, tc_b2, buf2, scratch, tid, 0);
    if (tid < 64){
        int b = tid>>3, n = tid&7;
        float a = tc_b3[n];
        #pragma unroll 4
        for (int j=0;j<D;j++) a = fmaf(buf2[b*D+j], tc_w3[j*NT+n], a);
        lgts[b*NT+n] = a;
    } else if (tid < 128){
        int r = (tid-64)>>3, p = tid&7;
        float m = -1e30f;
        for (int k=p*64;k<p*64+64;k++) m = fmaxf(m, wt[r*K+k]);
        pmax[r*8+p] = m;
    }
    __syncthreads();
    if (tid < 8){
        int b = tid; float m = -1e30f; int idx = 0;
        for (int n=0;n<NT;n++){ float v = lgts[b*NT+n]; if (v > m){ m=v; idx=n; } }
        float S = 0.f;
        for (int n=0;n<NT;n++) S += expf(lgts[b*NT+n]-m);
        ws[WS_VAL+b] = 1.0f/S;
        idxl[b] = idx;
    } else if (tid < 16){
        int r = tid-8; float m = -1e30f;
        for (int p=0;p<8;p++) m = fmaxf(m, pmax[r*8+p]);
        mxr[r] = m;
    }
    __syncthreads();
    for (int o=tid;o<B*K;o+=512){
        int b = o>>9, k = o&(K-1);
        int id = idxl[b];
        ws[WS_SEL+o] = wt[id*K+k] / (mxr[id] + 1e-8f);
    }
}

// swapped small layer: A-frags preloaded from GLOBAL (frag-interleaved, coalesced);
// B-frags linear from LDS; output written in next layer's B-frag layout.
template<int NKT_IN, bool ACT>
__device__ __forceinline__ void layerF(const short8* aw,
                                       const unsigned char* inb, unsigned char* outb,
                                       const float* biasp, int wv, int lg, int lc)
{
    const f32x4 z = {0.f,0.f,0.f,0.f};
    const int lane16 = (lg*16 + lc)*16;
    const int obase = ((wv>>1)<<10) + (((2*(wv&1) + (lg>>1))*16 + lc)<<4) + ((lg&1)<<3);
    f32x4 bb = z;
    if (biasp) bb = *(const f32x4*)(biasp + 16*wv + 4*lg);
    #pragma unroll
    for (int rt=0;rt<2;rt++){
        f32x4 d = z;
        #pragma unroll
        for (int kt=0;kt<NKT_IN;kt++){
            short8 bf = *(const short8*)(inb + ((rt*NKT_IN+kt)<<10) + lane16);
            d = __builtin_amdgcn_mfma_f32_16x16x32_bf16(aw[kt], bf, d, 0,0,0);
        }
        float o0 = d[0]+bb[0], o1 = d[1]+bb[1], o2 = d[2]+bb[2], o3 = d[3]+bb[3];
        if (ACT){ o0=lrelu(o0); o1=lrelu(o1); o2=lrelu(o2); o3=lrelu(o3); }
        uint2 u; u.x = cvtpk(o0,o1); u.y = cvtpk(o2,o3);
        *(uint2*)(outb + (rt<<12) + obase) = u;
    }
}

// ---------------- synth7 (R10 exact, best proven): fragment-interleaved; LDS=32768 ----------------
__global__ __launch_bounds__(512, 4) void synth7(
    const float* __restrict__ pos_b1, const float* __restrict__ pos_b2,
    const float* __restrict__ pos_b3, const float* __restrict__ sk_b2,
    const float* __restrict__ ws, float* __restrict__ out)
{
    __shared__ __align__(16) unsigned char lds[32768];
    unsigned char* abA = lds;
    unsigned char* abB = lds + 8192;
    unsigned char* PEb = abB;

    const int tid = threadIdx.x;
    const int wv = tid >> 6, lane = tid & 63, lg = lane >> 4, lc = lane & 15;
    const int lane16 = lane*16;
    const int t0 = blockIdx.x * 32;
    const unsigned short* wg16 = (const unsigned short*)((const char*)ws + WSBF_BYTE);
    const f32x4 z = {0.f,0.f,0.f,0.f};

    auto stage = [&](int elemoff, unsigned char* dst, int nchunks){
        const unsigned char* src = (const unsigned char*)(wg16 + elemoff);
        for (int c = wv; c < nchunks; c += 8)
            __builtin_amdgcn_global_load_lds(
                (const __attribute__((address_space(1))) unsigned int*)(src + (c<<10) + lane16),
                (__attribute__((address_space(3))) unsigned int*)(dst + (c<<10)), 16, 0, 0);
    };

    // ---- prefetch g1 A-frags (coalesced) + build pe (frag-interleaved) ----
    short8 aw1[2];
    #pragma unroll
    for (int kt=0;kt<2;kt++)
        aw1[kt] = *(const short8*)(wg16 + FP1 + ((wv*2+kt)<<9) + lane*8);
    for (int i = tid; i < 1024; i += 512){
        int r = i >> 5, p = i & 31;
        int j0 = 2*p;
        float pf = (float)(-1.0 + 2.0*(double)(t0+r)/32767.0);
        float v0 = pe_val(pf, j0);
        float v1 = pe_val(pf, j0+1);
        int kt = j0 >> 5, rem = j0 & 31;
        int by = (((r>>4)*2 + kt)<<10) + (((rem>>3)*16 + (r&15))<<4) + (rem&7)*2;
        *(unsigned*)(PEb + by) = cvtpk(v0, v1);
    }
    __syncthreads();

    // ---- phase A: issue next layer's frags before current MFMAs ----
    short8 awn[4];
    #pragma unroll
    for (int kt=0;kt<4;kt++)
        awn[kt] = *(const short8*)(wg16 + FP2 + ((wv*4+kt)<<9) + lane*8);
    layerF<2,true>(aw1, PEb, abA, pos_b1, wv, lg, lc);          // g1: pe -> abA
    __syncthreads();
    {
        short8 awp[4];
        #pragma unroll
        for (int kt=0;kt<4;kt++)
            awp[kt] = *(const short8*)(wg16 + FP3 + ((wv*4+kt)<<9) + lane*8);
        layerF<4,true>(awn, abA, abB, pos_b2, wv, lg, lc);      // g2: abA -> abB
        #pragma unroll
        for (int kt=0;kt<4;kt++) awn[kt] = awp[kt];
    }
    __syncthreads();
    {
        short8 awp[4];
        #pragma unroll
        for (int kt=0;kt<4;kt++)
            awp[kt] = *(const short8*)(wg16 + FS1 + ((wv*4+kt)<<9) + lane*8);
        layerF<4,false>(awn, abB, abA, pos_b3, wv, lg, lc);     // P: abB -> abA
        #pragma unroll
        for (int kt=0;kt<4;kt++) awn[kt] = awp[kt];
    }
    __syncthreads();
    layerF<4,false>(awn, abA, abB, nullptr, wv, lg, lc);        // A1: abA -> abB
    __syncthreads();

    // ---- stage w2 first 8KB over dead abA; h1 frags from abB + c1 ----
    stage(FS2, lds, 8);
    short8 hf[2][4];
    {
        const int b = lc & 7;
        const float* c1g = ws + WS_C1 + b*128;
        #pragma unroll
        for (int rtl=0;rtl<2;rtl++){
            int tl = 4*wv + 2*rtl + (lc>>3);
            int fr = tl >> 4, lrow = tl & 15;
            #pragma unroll
            for (int kt=0;kt<4;kt++){
                short8 a1v = *(const short8*)(abB + ((fr*4+kt)<<10) + ((lg*16+lrow)<<4));
                const float* cp = c1g + 32*kt + 8*lg;
                f32x4 c0 = *(const f32x4*)cp;
                f32x4 c1v = *(const f32x4*)(cp+4);
                float h[8];
                #pragma unroll
                for (int e=0;e<4;e++){
                    h[e]   = lrelu(bf2f(a1v[e])   + c0[e]);
                    h[4+e] = lrelu(bf2f(a1v[4+e]) + c1v[e]);
                }
                uint4 t4; t4.x=cvtpk(h[0],h[1]); t4.y=cvtpk(h[2],h[3]);
                t4.z=cvtpk(h[4],h[5]); t4.w=cvtpk(h[6],h[7]);
                hf[rtl][kt] = __builtin_bit_cast(short8, t4);
            }
        }
    }
    __syncthreads();   // abB reads done

    // ---- stage w2 rest (24KB over dead abB + tail), drain ----
    {
        const unsigned char* src = (const unsigned char*)(wg16 + FS2);
        for (int c = 8 + wv; c < 32; c += 8)
            __builtin_amdgcn_global_load_lds(
                (const __attribute__((address_space(1))) unsigned int*)(src + (c<<10) + lane16),
                (__attribute__((address_space(3))) unsigned int*)(lds + (c<<10)), 16, 0, 0);
    }
    VMCNT0; __syncthreads();

    // ---- layer2 (swapped, w2 frags linear from LDS) + in-register transpose ----
    short8 h2B[2][4];
    {
        const int sA = (2*(lg&1))*16 + lc;
        const int sB = sA + 16;
        const bool hi = (lg>>1) != 0;
        __builtin_amdgcn_s_setprio(1);
        #pragma unroll
        for (int kt2=0; kt2<4; kt2++){
            unsigned dpk[2][2][2];
            #pragma unroll
            for (int p=0;p<2;p++){
                int n2t = 2*kt2+p;
                short8 aw[4];
                #pragma unroll
                for (int kt=0;kt<4;kt++)
                    aw[kt] = *(const short8*)(lds + ((n2t*4+kt)<<10) + lane16);
                f32x4 b2 = *(const f32x4*)(sk_b2 + 16*n2t + 4*lg);
                #pragma unroll
                for (int rtl=0;rtl<2;rtl++){
                    f32x4 d = z;
                    #pragma unroll
                    for (int kt=0;kt<4;kt++)
                        d = __builtin_amdgcn_mfma_f32_16x16x32_bf16(aw[kt], hf[rtl][kt], d, 0,0,0);
                    float o0=lrelu(d[0]+b2[0]), o1=lrelu(d[1]+b2[1]);
                    float o2=lrelu(d[2]+b2[2]), o3=lrelu(d[3]+b2[3]);
                    dpk[p][rtl][0] = cvtpk(o0,o1);
                    dpk[p][rtl][1] = cvtpk(o2,o3);
                }
            }
            #pragma unroll
            for (int rtl=0;rtl<2;rtl++){
                unsigned a0 = (unsigned)__shfl((int)dpk[0][rtl][0], sA, 64);
                unsigned b0 = (unsigned)__shfl((int)dpk[1][rtl][0], sA, 64);
                unsigned a1 = (unsigned)__shfl((int)dpk[0][rtl][1], sA, 64);
                unsigned b1 = (unsigned)__shfl((int)dpk[1][rtl][1], sA, 64);
                unsigned a2 = (unsigned)__shfl((int)dpk[0][rtl][0], sB, 64);
                unsigned b2u= (unsigned)__shfl((int)dpk[1][rtl][0], sB, 64);
                unsigned a3 = (unsigned)__shfl((int)dpk[0][rtl][1], sB, 64);
                unsigned b3u= (unsigned)__shfl((int)dpk[1][rtl][1], sB, 64);
                uint4 uu;
                uu.x = hi ? b0 : a0;  uu.y = hi ? b1 : a1;
                uu.z = hi ? b2u : a2; uu.w = hi ? b3u : a3;
                h2B[rtl][kt2] = __builtin_bit_cast(short8, uu);
            }
        }
        __builtin_amdgcn_s_setprio(0);
    }
    __syncthreads();   // w2 reads done; LDS free for w3 dbuf

    // ---- layer3 (swapped) over 8 w3 16KB chunks (dbuf), fused exp/sel, q-summed ----
    float SSa[2], WWa[2];
    SSa[0]=0.f; SSa[1]=0.f; WWa[0]=0.f; WWa[1]=0.f;

    stage(FS3, lds, 16); VMCNT0; __syncthreads();
    const float* selg = ws + WS_SEL + (lc & 7)*512;
    const float* b3g  = ws + WS_B3P;
    for (int c=0;c<8;c++){
        const unsigned char* slot = lds + (c&1)*16384;
        if (c < 7) stage(FS3 + (c+1)*8192, lds + ((c+1)&1)*16384, 16);
        __builtin_amdgcn_s_setprio(1);
        #pragma unroll
        for (int nl=0;nl<4;nl++){
            int n3t = 4*c + nl;
            short8 bw[4];
            #pragma unroll
            for (int kt=0;kt<4;kt++)
                bw[kt] = *(const short8*)(slot + ((nl*4+kt)<<10) + lane16);
            f32x4 d3[2]; d3[0]=z; d3[1]=z;
            #pragma unroll
            for (int rtl=0;rtl<2;rtl++){
                #pragma unroll
                for (int kt=0;kt<4;kt++)
                    d3[rtl] = __builtin_amdgcn_mfma_f32_16x16x32_bf16(bw[kt], h2B[rtl][kt], d3[rtl], 0,0,0);
            }
            f32x4 b3 = *(const f32x4*)(b3g + 16*n3t + 4*lg);
            f32x4 sv = *(const f32x4*)(selg + 16*n3t + 4*lg);
            #pragma unroll
            for (int rtl=0;rtl<2;rtl++){
                float e0 = exp2fast(fmaf(d3[rtl][0], LOG2E, b3[0]));
                float e1 = exp2fast(fmaf(d3[rtl][1], LOG2E, b3[1]));
                float e2 = exp2fast(fmaf(d3[rtl][2], LOG2E, b3[2]));
                float e3 = exp2fast(fmaf(d3[rtl][3], LOG2E, b3[3]));
                SSa[rtl] += (e0+e1) + (e2+e3);
                float w = fmaf(e0, sv[0], fmaf(e1, sv[1], fmaf(e2, sv[2], e3*sv[3])));
                WWa[rtl] += w;
            }
        }
        __builtin_amdgcn_s_setprio(0);
        VMCNT0; __syncthreads();
    }

    // ---- epilogue: reduce over lg, env interp, write ----
    #pragma unroll
    for (int rtl=0;rtl<2;rtl++){
        float s = SSa[rtl];
        float w = WWa[rtl];
        s += __shfl_xor(s, 16, 64); s += __shfl_xor(s, 32, 64);
        w += __shfl_xor(w, 16, 64); w += __shfl_xor(w, 32, 64);
        if (lg == 0){
            int tl = 4*wv + 2*rtl + (lc>>3);
            int b  = lc & 7;
            int t  = t0 + tl;
            float coord = (t + 0.5f)*(1.0f/256.0f) - 0.5f;
            float fi = floorf(coord); float frac = coord - fi;
            int i0 = (int)fi; int i1 = i0 + 1;
            i0 = min(max(i0,0),NFRM-1); i1 = min(max(i1,0),NFRM-1);
            float e0 = ws[WS_ENV8 + b*NFRM + i0], e1 = ws[WS_ENV8 + b*NFRM + i1];
            float envv = e0*(1.0f-frac) + e1*frac;
            out[b*T_SAMP + t] = (w/s) * envv * ws[WS_VAL+b];
        }
    }
}

extern "C" void kernel_launch(void* const* d_in, const int* in_sizes, int n_in,
                              void* d_out, int out_size, void* d_ws, size_t ws_size,
                              hipStream_t stream)
{
    (void)in_sizes; (void)n_in; (void)out_size;
    const float* x       = (const float*)d_in[0];
    const float* wt      = (const float*)d_in[1];
    const float* tc_w1   = (const float*)d_in[2];
    const float* tc_b1   = (const float*)d_in[3];
    const float* tc_w2   = (const float*)d_in[4];
    const float* tc_b2   = (const float*)d_in[5];
    const float* tc_w3   = (const float*)d_in[6];
    const float* tc_b3   = (const float*)d_in[7];
    const float* env_w1  = (const float*)d_in[8];
    const float* env_b1  = (const float*)d_in[9];
    const float* env_w2  = (const float*)d_in[10];
    const float* env_b2  = (const float*)d_in[11];
    const float* env_w3  = (const float*)d_in[12];
    const float* env_b3  = (const float*)d_in[13];
    const float* pos_w1  = (const float*)d_in[14];
    const float* pos_b1  = (const float*)d_in[15];
    const float* pos_w2  = (const float*)d_in[16];
    const float* pos_b2  = (const float*)d_in[17];
    const float* pos_w3  = (const float*)d_in[18];
    const float* pos_b3  = (const float*)d_in[19];
    const float* sk_w1   = (const float*)d_in[20];
    const float* sk_b1   = (const float*)d_in[21];
    const float* sk_w2   = (const float*)d_in[22];
    const float* sk_b2   = (const float*)d_in[23];
    const float* sk_w3   = (const float*)d_in[24];
    const float* sk_b3   = (const float*)d_in[25];
    float* ws  = (float*)d_ws;
    float* out = (float*)d_out;

    if (ws_size < (size_t)WS_NEED) return;  // ws proven >= WS_NEED on this harness

    hipLaunchKernelGGL(setup_kernel, dim3(2 + (WTOT+511)/512), dim3(512), 0, stream,
        x, wt, tc_w1, tc_b1, tc_w2, tc_b2, tc_w3, tc_b3,
        env_w1, env_b1, env_w2, env_b2, env_w3, env_b3,
        sk_w1, sk_b1, pos_w1, pos_w2, pos_w3, sk_w2, sk_w3, sk_b3, ws);

    hipLaunchKernelGGL(synth7, dim3(T_SAMP/32), dim3(512), 0, stream,
        pos_b1, pos_b2, pos_b3, sk_b2, ws, out);
}